// Round 1
// baseline (533.664 us; speedup 1.0000x reference)
//
#include <hip/hip_runtime.h>

#define NB 8
#define NC 4
#define HH 256
#define WW 256
#define HW_ (HH * WW)
#define NSL 24   // NB * (NC-1)

__device__ inline double block_reduce(double v, double* sbuf) {
  int lane = threadIdx.x & 63;
  int wid  = threadIdx.x >> 6;
  #pragma unroll
  for (int o = 32; o > 0; o >>= 1) v += __shfl_down(v, o, 64);
  if (lane == 0) sbuf[wid] = v;
  __syncthreads();
  double r = 0.0;
  if (threadIdx.x == 0) {
    #pragma unroll
    for (int i = 0; i < 4; ++i) r += sbuf[i];
  }
  __syncthreads();
  return r;  // valid in thread 0 only
}

__global__ void k_zero(double* acc) {
  if (threadIdx.x < 8) acc[threadIdx.x] = 0.0;
}

__global__ __launch_bounds__(256) void k_softmax_ce(
    const float* __restrict__ pred, const int* __restrict__ tgt,
    float* __restrict__ pbuf, double* __restrict__ acc) {
  __shared__ double sbuf[4];
  int gid = blockIdx.x * 256 + threadIdx.x;  // 0 .. NB*HW_-1
  int n   = gid >> 16;
  int pix = gid & (HW_ - 1);
  const float* pp = pred + (size_t)n * NC * HW_ + pix;
  float x0 = pp[0];
  float x1 = pp[HW_];
  float x2 = pp[2 * HW_];
  float x3 = pp[3 * HW_];
  float mx = fmaxf(fmaxf(x0, x1), fmaxf(x2, x3));
  float e0 = expf(x0 - mx), e1 = expf(x1 - mx), e2 = expf(x2 - mx), e3 = expf(x3 - mx);
  float lse = mx + logf(e0 + e1 + e2 + e3);
  int t = tgt[gid];
  float xt = (t == 0) ? x0 : (t == 1) ? x1 : (t == 2) ? x2 : x3;
  float ce = lse - xt;  // -log_p[target]
  int base = (n * 3) * HW_ + pix;
  pbuf[base]           = expf(x1 - lse);
  pbuf[base + HW_]     = expf(x2 - lse);
  pbuf[base + 2 * HW_] = expf(x3 - lse);
  double r = block_reduce((double)ce, sbuf);
  if (threadIdx.x == 0) atomicAdd(&acc[0], r);
}

// Binary 1D distance transform along H (columns), exact reference semantics:
// d = min(dl, dr) with NOSEED=1e4 when absent, store d*d.
__global__ __launch_bounds__(256) void k_col(const int* __restrict__ tgt,
    const float* __restrict__ pbuf, float* __restrict__ gbuf) {
  int s    = blockIdx.x;  // slice 0..23  (n = s/3, c = s%3+1)
  int mode = blockIdx.y;  // 0 = fg (tgt==c), 1 = bg (tgt!=c), 2 = pred (p>=0.5)
  int w    = threadIdx.x;
  int n = s / 3, c = s - n * 3 + 1;
  const int*   tg = tgt  + (size_t)n * HW_;
  const float* pb = pbuf + (size_t)s * HW_;
  float* g = gbuf + ((size_t)mode * NSL + s) * HW_;
  int left = -1;
  #pragma unroll 4
  for (int h = 0; h < HH; ++h) {
    int off = h * WW + w;
    bool seed = (mode == 0) ? (tg[off] == c)
              : (mode == 1) ? (tg[off] != c)
                            : (pb[off] >= 0.5f);
    if (seed) left = h;
    g[off] = (left >= 0) ? (float)(h - left) : 10000.0f;
  }
  int right = -1;
  #pragma unroll 4
  for (int h = HH - 1; h >= 0; --h) {
    int off = h * WW + w;
    bool seed = (mode == 0) ? (tg[off] == c)
              : (mode == 1) ? (tg[off] != c)
                            : (pb[off] >= 0.5f);
    if (seed) right = h;
    float dr = (right >= 0) ? (float)(right - h) : 10000.0f;
    float d  = fminf(g[off], dr);
    g[off] = d * d;
  }
}

// Row-wise exact lower envelope: d[j] = min_y g[y] + (j-y)^2, for all three
// transforms at once; then fused accumulation of bd / hd-term1 / hd-term2.
__global__ __launch_bounds__(256) void k_row(const float* __restrict__ gbuf,
    const float* __restrict__ pbuf, const int* __restrict__ tgt,
    double* __restrict__ acc) {
  __shared__ alignas(16) float lf[WW];
  __shared__ alignas(16) float lb[WW];
  __shared__ alignas(16) float lq[WW];
  __shared__ double sbuf[4];
  int s = blockIdx.x, h = blockIdx.y, w = threadIdx.x;
  int n = s / 3, c = s - n * 3 + 1;
  size_t off = (size_t)s * HW_ + (size_t)h * WW + w;
  lf[w] = gbuf[off];
  lb[w] = gbuf[(size_t)NSL * HW_ + off];
  lq[w] = gbuf[2 * (size_t)NSL * HW_ + off];
  __syncthreads();
  float jf = (float)w;
  float mfg = 1e18f, mbg = 1e18f, mpr = 1e18f;
  #pragma unroll 8
  for (int y = 0; y < WW; y += 4) {
    float4 f = *(const float4*)&lf[y];
    float4 b = *(const float4*)&lb[y];
    float4 q = *(const float4*)&lq[y];
    float t0 = jf - (float)y;
    float t1 = t0 - 1.0f, t2 = t0 - 2.0f, t3 = t0 - 3.0f;
    float s0 = t0 * t0, s1 = t1 * t1, s2 = t2 * t2, s3 = t3 * t3;
    mfg = fminf(mfg, f.x + s0); mfg = fminf(mfg, f.y + s1);
    mfg = fminf(mfg, f.z + s2); mfg = fminf(mfg, f.w + s3);
    mbg = fminf(mbg, b.x + s0); mbg = fminf(mbg, b.y + s1);
    mbg = fminf(mbg, b.z + s2); mbg = fminf(mbg, b.w + s3);
    mpr = fminf(mpr, q.x + s0); mpr = fminf(mpr, q.y + s1);
    mpr = fminf(mpr, q.z + s2); mpr = fminf(mpr, q.w + s3);
  }
  float dfg = sqrtf(mfg), dbg = sqrtf(mbg), dpr = sqrtf(mpr);
  float p  = pbuf[off];
  float gt = (tgt[(size_t)n * HW_ + h * WW + w] == c) ? 1.0f : 0.0f;
  double r;
  r = block_reduce((double)(p * (dfg - dbg)), sbuf);   // bd
  if (threadIdx.x == 0) atomicAdd(&acc[1], r);
  r = block_reduce((double)(p * dfg * dfg), sbuf);     // hd term1
  if (threadIdx.x == 0) atomicAdd(&acc[2], r);
  r = block_reduce((double)(gt * dpr * dpr), sbuf);    // hd term2
  if (threadIdx.x == 0) atomicAdd(&acc[3], r);
}

__global__ void k_final(const double* __restrict__ acc, float* __restrict__ out) {
  if (threadIdx.x == 0) {
    double ce = acc[0] / (double)(NB * HW_);
    double bd = acc[1] / (double)NSL;
    double hd = (acc[2] + acc[3]) / ((double)HW_ * (double)(2 * NB * (NC - 1)));
    out[0] = (float)(ce + 0.5 * bd + 0.5 * hd);
    out[1] = (float)ce;
    out[2] = (float)bd;
    out[3] = (float)hd;
  }
}

extern "C" void kernel_launch(void* const* d_in, const int* in_sizes, int n_in,
                              void* d_out, int out_size, void* d_ws, size_t ws_size,
                              hipStream_t stream) {
  (void)in_sizes; (void)n_in; (void)out_size; (void)ws_size;
  const float* pred = (const float*)d_in[0];
  const int*   tgt  = (const int*)d_in[1];
  float* out = (float*)d_out;
  char* ws = (char*)d_ws;
  double* acc = (double*)ws;                              // 8 doubles
  float* pbuf = (float*)(ws + 256);                       // 24*HW floats
  float* gbuf = (float*)(ws + 256 + (size_t)NSL * HW_ * 4); // 3 * 24*HW floats

  hipLaunchKernelGGL(k_zero, dim3(1), dim3(64), 0, stream, acc);
  hipLaunchKernelGGL(k_softmax_ce, dim3((NB * HW_) / 256), dim3(256), 0, stream,
                     pred, tgt, pbuf, acc);
  hipLaunchKernelGGL(k_col, dim3(NSL, 3), dim3(256), 0, stream, tgt, pbuf, gbuf);
  hipLaunchKernelGGL(k_row, dim3(NSL, HH), dim3(256), 0, stream, gbuf, pbuf, tgt, acc);
  hipLaunchKernelGGL(k_final, dim3(1), dim3(1), 0, stream, acc, out);
}

// Round 2
// 375.949 us; speedup vs baseline: 1.4195x; 1.4195x over previous
//
#include <hip/hip_runtime.h>

#define NB 8
#define NC 4
#define HH 256
#define WW 256
#define HW_ (HH * WW)
#define NSL 24   // NB * (NC-1)

__device__ inline double block_reduce(double v, double* sbuf) {
  int lane = threadIdx.x & 63;
  int wid  = threadIdx.x >> 6;
  #pragma unroll
  for (int o = 32; o > 0; o >>= 1) v += __shfl_down(v, o, 64);
  if (lane == 0) sbuf[wid] = v;
  __syncthreads();
  double r = 0.0;
  if (threadIdx.x == 0) {
    #pragma unroll
    for (int i = 0; i < 4; ++i) r += sbuf[i];
  }
  __syncthreads();
  return r;  // valid in thread 0 only
}

__global__ void k_zero(double* acc) {
  if (threadIdx.x < 8) acc[threadIdx.x] = 0.0;
}

__global__ __launch_bounds__(256) void k_softmax_ce(
    const float* __restrict__ pred, const int* __restrict__ tgt,
    float* __restrict__ pbuf, double* __restrict__ acc) {
  __shared__ double sbuf[4];
  int gid = blockIdx.x * 256 + threadIdx.x;  // 0 .. NB*HW_-1
  int n   = gid >> 16;
  int pix = gid & (HW_ - 1);
  const float* pp = pred + (size_t)n * NC * HW_ + pix;
  float x0 = pp[0];
  float x1 = pp[HW_];
  float x2 = pp[2 * HW_];
  float x3 = pp[3 * HW_];
  float mx = fmaxf(fmaxf(x0, x1), fmaxf(x2, x3));
  float e0 = expf(x0 - mx), e1 = expf(x1 - mx), e2 = expf(x2 - mx), e3 = expf(x3 - mx);
  float sum = e0 + e1 + e2 + e3;
  float lse = mx + logf(sum);
  int t = tgt[gid];
  float xt = (t == 0) ? x0 : (t == 1) ? x1 : (t == 2) ? x2 : x3;
  float ce = lse - xt;  // -log_p[target]
  float inv = 1.0f / sum;
  int base = (n * 3) * HW_ + pix;
  pbuf[base]           = e1 * inv;
  pbuf[base + HW_]     = e2 * inv;
  pbuf[base + 2 * HW_] = e3 * inv;
  double r = block_reduce((double)ce, sbuf);
  if (threadIdx.x == 0) atomicAdd(&acc[0], r);
}

// Column binary DT via exact outward search: one block per (slice, row h),
// 256 threads = columns w. First radius r with a seed at h-r or h+r is the
// exact 1D nearest-seed distance. All three seed modes share row loads.
__global__ __launch_bounds__(256) void k_coldt(const int* __restrict__ tgt,
    const float* __restrict__ pbuf, float* __restrict__ gbuf) {
  int bh = blockIdx.x;            // s*HH + h
  int h  = bh & (HH - 1);
  int s  = bh >> 8;
  int n = s / 3, c = s - n * 3 + 1;
  int w = threadIdx.x;
  const int*   tg = tgt  + (size_t)n * HW_ + w;
  const float* pb = pbuf + (size_t)s * HW_ + w;
  int   t0 = tg[h * WW];
  float p0 = pb[h * WW];
  float dF = (t0 == c)    ? 0.f : -1.f;   // fg: tgt == c
  float dB = (t0 != c)    ? 0.f : -1.f;   // bg: tgt != c
  float dP = (p0 >= 0.5f) ? 0.f : -1.f;   // pred: p >= 0.5
  for (int r = 1; r < HH; ++r) {
    bool needT = !__all((dF >= 0.f) & (dB >= 0.f));
    bool needP = !__all(dP >= 0.f);
    if (!needT && !needP) break;
    int hu = h - r, hd = h + r;
    bool up = hu >= 0, dn = hd < HH;
    int cu = up ? hu : 0, cd = dn ? hd : (HH - 1);
    float rf = (float)r;
    if (needT) {
      int tu = tg[cu * WW], td = tg[cd * WW];
      if (dF < 0.f && ((up && tu == c) || (dn && td == c))) dF = rf;
      if (dB < 0.f && ((up && tu != c) || (dn && td != c))) dB = rf;
    }
    if (needP) {
      float pu = pb[cu * WW], pd = pb[cd * WW];
      if (dP < 0.f && ((up && pu >= 0.5f) || (dn && pd >= 0.5f))) dP = rf;
    }
  }
  if (dF < 0.f) dF = 10000.0f;
  if (dB < 0.f) dB = 10000.0f;
  if (dP < 0.f) dP = 10000.0f;
  size_t off = (size_t)s * HW_ + (size_t)h * WW + w;
  gbuf[off]                       = dF * dF;
  gbuf[(size_t)NSL * HW_ + off]   = dB * dB;
  gbuf[2 * (size_t)NSL * HW_ + off] = dP * dP;
}

// Row-wise exact lower envelope via outward search with pruning:
// m = min_y g[y] + (j-y)^2; any y with (j-y)^2 >= m can't win, so expand r
// and stop when r^2 >= m (wave-wide). Identical f32 adds/mins as brute force.
__global__ __launch_bounds__(256) void k_row(const float* __restrict__ gbuf,
    const float* __restrict__ pbuf, const int* __restrict__ tgt,
    double* __restrict__ acc) {
  __shared__ alignas(16) float lf[WW];
  __shared__ alignas(16) float lb[WW];
  __shared__ alignas(16) float lq[WW];
  __shared__ double sbuf[4];
  int bh = blockIdx.x;            // s*HH + h
  int h  = bh & (HH - 1);
  int s  = bh >> 8;
  int n = s / 3, c = s - n * 3 + 1;
  int w = threadIdx.x;
  size_t off = (size_t)s * HW_ + (size_t)h * WW + w;
  lf[w] = gbuf[off];
  lb[w] = gbuf[(size_t)NSL * HW_ + off];
  lq[w] = gbuf[2 * (size_t)NSL * HW_ + off];
  __syncthreads();
  float mF = lf[w], mB = lb[w], mQ = lq[w];
  for (int r = 1; r < WW; ++r) {
    float rr = (float)(r * r);
    if (__all(rr >= mF)) break;
    int jl = w - r, jr = w + r;
    if (jl >= 0) mF = fminf(mF, lf[jl] + rr);
    if (jr < WW) mF = fminf(mF, lf[jr] + rr);
  }
  for (int r = 1; r < WW; ++r) {
    float rr = (float)(r * r);
    if (__all(rr >= mB)) break;
    int jl = w - r, jr = w + r;
    if (jl >= 0) mB = fminf(mB, lb[jl] + rr);
    if (jr < WW) mB = fminf(mB, lb[jr] + rr);
  }
  for (int r = 1; r < WW; ++r) {
    float rr = (float)(r * r);
    if (__all(rr >= mQ)) break;
    int jl = w - r, jr = w + r;
    if (jl >= 0) mQ = fminf(mQ, lq[jl] + rr);
    if (jr < WW) mQ = fminf(mQ, lq[jr] + rr);
  }
  float dfg = sqrtf(mF), dbg = sqrtf(mB), dpr = sqrtf(mQ);
  float p  = pbuf[off];
  float gt = (tgt[(size_t)n * HW_ + h * WW + w] == c) ? 1.0f : 0.0f;
  double r;
  r = block_reduce((double)(p * (dfg - dbg)), sbuf);   // bd
  if (threadIdx.x == 0) atomicAdd(&acc[1], r);
  r = block_reduce((double)(p * dfg * dfg), sbuf);     // hd term1
  if (threadIdx.x == 0) atomicAdd(&acc[2], r);
  r = block_reduce((double)(gt * dpr * dpr), sbuf);    // hd term2
  if (threadIdx.x == 0) atomicAdd(&acc[3], r);
}

__global__ void k_final(const double* __restrict__ acc, float* __restrict__ out) {
  if (threadIdx.x == 0) {
    double ce = acc[0] / (double)(NB * HW_);
    double bd = acc[1] / (double)NSL;
    double hd = (acc[2] + acc[3]) / ((double)HW_ * (double)(2 * NB * (NC - 1)));
    out[0] = (float)(ce + 0.5 * bd + 0.5 * hd);
    out[1] = (float)ce;
    out[2] = (float)bd;
    out[3] = (float)hd;
  }
}

extern "C" void kernel_launch(void* const* d_in, const int* in_sizes, int n_in,
                              void* d_out, int out_size, void* d_ws, size_t ws_size,
                              hipStream_t stream) {
  (void)in_sizes; (void)n_in; (void)out_size; (void)ws_size;
  const float* pred = (const float*)d_in[0];
  const int*   tgt  = (const int*)d_in[1];
  float* out = (float*)d_out;
  char* ws = (char*)d_ws;
  double* acc = (double*)ws;                                // 8 doubles
  float* pbuf = (float*)(ws + 256);                         // 24*HW floats
  float* gbuf = (float*)(ws + 256 + (size_t)NSL * HW_ * 4); // 3 * 24*HW floats

  hipLaunchKernelGGL(k_zero, dim3(1), dim3(64), 0, stream, acc);
  hipLaunchKernelGGL(k_softmax_ce, dim3((NB * HW_) / 256), dim3(256), 0, stream,
                     pred, tgt, pbuf, acc);
  hipLaunchKernelGGL(k_coldt, dim3(NSL * HH), dim3(256), 0, stream, tgt, pbuf, gbuf);
  hipLaunchKernelGGL(k_row, dim3(NSL * HH), dim3(256), 0, stream, gbuf, pbuf, tgt, acc);
  hipLaunchKernelGGL(k_final, dim3(1), dim3(1), 0, stream, acc, out);
}

// Round 3
// 145.123 us; speedup vs baseline: 3.6773x; 2.5906x over previous
//
#include <hip/hip_runtime.h>

#define NB 8
#define NC 4
#define HH 256
#define WW 256
#define HW_ (HH * WW)
#define NSL 24   // NB * (NC-1)
#define NBKT 32  // spread-atomic buckets, one 64B line each: bkt[b*8 + q], q=0..3

__device__ inline double block_reduce(double v, double* sbuf) {
  int lane = threadIdx.x & 63;
  int wid  = threadIdx.x >> 6;
  #pragma unroll
  for (int o = 32; o > 0; o >>= 1) v += __shfl_down(v, o, 64);
  if (lane == 0) sbuf[wid] = v;
  __syncthreads();
  double r = 0.0;
  if (threadIdx.x == 0) {
    #pragma unroll
    for (int i = 0; i < 4; ++i) r += sbuf[i];
  }
  __syncthreads();
  return r;  // valid in thread 0 only
}

__global__ void k_zero(double* bkt) {
  int t = threadIdx.x;
  if (t < NBKT * 8) bkt[t] = 0.0;
}

__global__ __launch_bounds__(256) void k_softmax_ce(
    const float* __restrict__ pred, const int* __restrict__ tgt,
    float* __restrict__ pbuf, double* __restrict__ bkt) {
  __shared__ double sbuf[4];
  int gid = blockIdx.x * 256 + threadIdx.x;  // 0 .. NB*HW_-1
  int n   = gid >> 16;
  int pix = gid & (HW_ - 1);
  const float* pp = pred + (size_t)n * NC * HW_ + pix;
  float x0 = pp[0];
  float x1 = pp[HW_];
  float x2 = pp[2 * HW_];
  float x3 = pp[3 * HW_];
  float mx = fmaxf(fmaxf(x0, x1), fmaxf(x2, x3));
  float e0 = expf(x0 - mx), e1 = expf(x1 - mx), e2 = expf(x2 - mx), e3 = expf(x3 - mx);
  float sum = e0 + e1 + e2 + e3;
  float lse = mx + logf(sum);
  int t = tgt[gid];
  float xt = (t == 0) ? x0 : (t == 1) ? x1 : (t == 2) ? x2 : x3;
  float ce = lse - xt;  // -log_p[target]
  float inv = 1.0f / sum;
  int base = (n * 3) * HW_ + pix;
  pbuf[base]           = e1 * inv;
  pbuf[base + HW_]     = e2 * inv;
  pbuf[base + 2 * HW_] = e3 * inv;
  double r = block_reduce((double)ce, sbuf);
  if (threadIdx.x == 0) atomicAdd(&bkt[(blockIdx.x & (NBKT - 1)) * 8 + 0], r);
}

// Column binary DT via exact outward search: one block per (slice, row h),
// 256 threads = columns w. First radius r with a seed at h-r or h+r is the
// exact 1D nearest-seed distance. All three seed modes share row loads.
__global__ __launch_bounds__(256) void k_coldt(const int* __restrict__ tgt,
    const float* __restrict__ pbuf, float* __restrict__ gbuf) {
  int bh = blockIdx.x;            // s*HH + h
  int h  = bh & (HH - 1);
  int s  = bh >> 8;
  int n = s / 3, c = s - n * 3 + 1;
  int w = threadIdx.x;
  const int*   tg = tgt  + (size_t)n * HW_ + w;
  const float* pb = pbuf + (size_t)s * HW_ + w;
  int   t0 = tg[h * WW];
  float p0 = pb[h * WW];
  float dF = (t0 == c)    ? 0.f : -1.f;   // fg: tgt == c
  float dB = (t0 != c)    ? 0.f : -1.f;   // bg: tgt != c
  float dP = (p0 >= 0.5f) ? 0.f : -1.f;   // pred: p >= 0.5
  for (int r = 1; r < HH; ++r) {
    bool needT = !__all((dF >= 0.f) & (dB >= 0.f));
    bool needP = !__all(dP >= 0.f);
    if (!needT && !needP) break;
    int hu = h - r, hd = h + r;
    bool up = hu >= 0, dn = hd < HH;
    int cu = up ? hu : 0, cd = dn ? hd : (HH - 1);
    float rf = (float)r;
    if (needT) {
      int tu = tg[cu * WW], td = tg[cd * WW];
      if (dF < 0.f && ((up && tu == c) || (dn && td == c))) dF = rf;
      if (dB < 0.f && ((up && tu != c) || (dn && td != c))) dB = rf;
    }
    if (needP) {
      float pu = pb[cu * WW], pd = pb[cd * WW];
      if (dP < 0.f && ((up && pu >= 0.5f) || (dn && pd >= 0.5f))) dP = rf;
    }
  }
  if (dF < 0.f) dF = 10000.0f;
  if (dB < 0.f) dB = 10000.0f;
  if (dP < 0.f) dP = 10000.0f;
  size_t off = (size_t)s * HW_ + (size_t)h * WW + w;
  gbuf[off]                         = dF * dF;
  gbuf[(size_t)NSL * HW_ + off]     = dB * dB;
  gbuf[2 * (size_t)NSL * HW_ + off] = dP * dP;
}

// Row-wise exact lower envelope via outward search with pruning:
// m = min_y g[y] + (j-y)^2; any y with (j-y)^2 >= m can't win, so expand r
// and stop when r^2 >= m (wave-wide). Identical f32 adds/mins as brute force.
__global__ __launch_bounds__(256) void k_row(const float* __restrict__ gbuf,
    const float* __restrict__ pbuf, const int* __restrict__ tgt,
    double* __restrict__ bkt) {
  __shared__ alignas(16) float lf[WW];
  __shared__ alignas(16) float lb[WW];
  __shared__ alignas(16) float lq[WW];
  __shared__ double sbuf[4];
  int bh = blockIdx.x;            // s*HH + h
  int h  = bh & (HH - 1);
  int s  = bh >> 8;
  int n = s / 3, c = s - n * 3 + 1;
  int w = threadIdx.x;
  size_t off = (size_t)s * HW_ + (size_t)h * WW + w;
  lf[w] = gbuf[off];
  lb[w] = gbuf[(size_t)NSL * HW_ + off];
  lq[w] = gbuf[2 * (size_t)NSL * HW_ + off];
  __syncthreads();
  float mF = lf[w], mB = lb[w], mQ = lq[w];
  for (int r = 1; r < WW; ++r) {
    float rr = (float)(r * r);
    if (__all(rr >= mF)) break;
    int jl = w - r, jr = w + r;
    if (jl >= 0) mF = fminf(mF, lf[jl] + rr);
    if (jr < WW) mF = fminf(mF, lf[jr] + rr);
  }
  for (int r = 1; r < WW; ++r) {
    float rr = (float)(r * r);
    if (__all(rr >= mB)) break;
    int jl = w - r, jr = w + r;
    if (jl >= 0) mB = fminf(mB, lb[jl] + rr);
    if (jr < WW) mB = fminf(mB, lb[jr] + rr);
  }
  for (int r = 1; r < WW; ++r) {
    float rr = (float)(r * r);
    if (__all(rr >= mQ)) break;
    int jl = w - r, jr = w + r;
    if (jl >= 0) mQ = fminf(mQ, lq[jl] + rr);
    if (jr < WW) mQ = fminf(mQ, lq[jr] + rr);
  }
  float dfg = sqrtf(mF), dbg = sqrtf(mB), dpr = sqrtf(mQ);
  float p  = pbuf[off];
  float gt = (tgt[(size_t)n * HW_ + h * WW + w] == c) ? 1.0f : 0.0f;
  int b = (blockIdx.x & (NBKT - 1)) * 8;
  double r;
  r = block_reduce((double)(p * (dfg - dbg)), sbuf);   // bd
  if (threadIdx.x == 0) atomicAdd(&bkt[b + 1], r);
  r = block_reduce((double)(p * dfg * dfg), sbuf);     // hd term1
  if (threadIdx.x == 0) atomicAdd(&bkt[b + 2], r);
  r = block_reduce((double)(gt * dpr * dpr), sbuf);    // hd term2
  if (threadIdx.x == 0) atomicAdd(&bkt[b + 3], r);
}

__global__ void k_final(const double* __restrict__ bkt, float* __restrict__ out) {
  int t = threadIdx.x;  // 64 threads, one wave
  double ce = 0.0, bd = 0.0, t1 = 0.0, t2 = 0.0;
  if (t < NBKT) {
    ce = bkt[t * 8 + 0];
    bd = bkt[t * 8 + 1];
    t1 = bkt[t * 8 + 2];
    t2 = bkt[t * 8 + 3];
  }
  #pragma unroll
  for (int o = 32; o > 0; o >>= 1) {
    ce += __shfl_down(ce, o, 64);
    bd += __shfl_down(bd, o, 64);
    t1 += __shfl_down(t1, o, 64);
    t2 += __shfl_down(t2, o, 64);
  }
  if (t == 0) {
    ce /= (double)(NB * HW_);
    bd /= (double)NSL;
    double hd = (t1 + t2) / ((double)HW_ * (double)(2 * NB * (NC - 1)));
    out[0] = (float)(ce + 0.5 * bd + 0.5 * hd);
    out[1] = (float)ce;
    out[2] = (float)bd;
    out[3] = (float)hd;
  }
}

extern "C" void kernel_launch(void* const* d_in, const int* in_sizes, int n_in,
                              void* d_out, int out_size, void* d_ws, size_t ws_size,
                              hipStream_t stream) {
  (void)in_sizes; (void)n_in; (void)out_size; (void)ws_size;
  const float* pred = (const float*)d_in[0];
  const int*   tgt  = (const int*)d_in[1];
  float* out = (float*)d_out;
  char* ws = (char*)d_ws;
  double* bkt = (double*)ws;                                 // 32*8 doubles = 2KB
  float* pbuf = (float*)(ws + 2048);                         // 24*HW floats
  float* gbuf = (float*)(ws + 2048 + (size_t)NSL * HW_ * 4); // 3 * 24*HW floats

  hipLaunchKernelGGL(k_zero, dim3(1), dim3(256), 0, stream, bkt);
  hipLaunchKernelGGL(k_softmax_ce, dim3((NB * HW_) / 256), dim3(256), 0, stream,
                     pred, tgt, pbuf, bkt);
  hipLaunchKernelGGL(k_coldt, dim3(NSL * HH), dim3(256), 0, stream, tgt, pbuf, gbuf);
  hipLaunchKernelGGL(k_row, dim3(NSL * HH), dim3(256), 0, stream, gbuf, pbuf, tgt, bkt);
  hipLaunchKernelGGL(k_final, dim3(1), dim3(64), 0, stream, bkt, out);
}

// Round 4
// 96.091 us; speedup vs baseline: 5.5538x; 1.5103x over previous
//
#include <hip/hip_runtime.h>

#define NB 8
#define NC 4
#define HH 256
#define WW 256
#define HW_ (HH * WW)
#define NSL 24   // NB * (NC-1)
#define NBKT 32  // spread-atomic buckets, one 64B line each: bkt[b*8 + q]

typedef unsigned long long u64;

__device__ inline double block_reduce(double v, double* sbuf) {
  int lane = threadIdx.x & 63;
  int wid  = threadIdx.x >> 6;
  #pragma unroll
  for (int o = 32; o > 0; o >>= 1) v += __shfl_down(v, o, 64);
  if (lane == 0) sbuf[wid] = v;
  __syncthreads();
  double r = 0.0;
  if (threadIdx.x == 0) {
    #pragma unroll
    for (int i = 0; i < 4; ++i) r += sbuf[i];
  }
  __syncthreads();
  return r;  // valid in thread 0 only
}

__global__ void k_zero(double* bkt) {
  int t = threadIdx.x;
  if (t < NBKT * 8) bkt[t] = 0.0;
}

__global__ __launch_bounds__(256) void k_softmax_ce(
    const float* __restrict__ pred, const int* __restrict__ tgt,
    float* __restrict__ pbuf, double* __restrict__ bkt) {
  __shared__ double sbuf[4];
  int gid = blockIdx.x * 256 + threadIdx.x;  // 0 .. NB*HW_-1
  int n   = gid >> 16;
  int pix = gid & (HW_ - 1);
  const float* pp = pred + (size_t)n * NC * HW_ + pix;
  float x0 = pp[0];
  float x1 = pp[HW_];
  float x2 = pp[2 * HW_];
  float x3 = pp[3 * HW_];
  float mx = fmaxf(fmaxf(x0, x1), fmaxf(x2, x3));
  float e0 = expf(x0 - mx), e1 = expf(x1 - mx), e2 = expf(x2 - mx), e3 = expf(x3 - mx);
  float sum = e0 + e1 + e2 + e3;
  float lse = mx + logf(sum);
  int t = tgt[gid];
  float xt = (t == 0) ? x0 : (t == 1) ? x1 : (t == 2) ? x2 : x3;
  float ce = lse - xt;  // -log_p[target]
  float inv = 1.0f / sum;
  int base = (n * 3) * HW_ + pix;
  pbuf[base]           = e1 * inv;
  pbuf[base + HW_]     = e2 * inv;
  pbuf[base + 2 * HW_] = e3 * inv;
  double r = block_reduce((double)ce, sbuf);
  if (threadIdx.x == 0) atomicAdd(&bkt[(blockIdx.x & (NBKT - 1)) * 8 + 0], r);
}

// Build bit-transposed column seed masks. Block = (slice s, 64-col tile wt);
// 4 waves, wave v owns row-stripe [64v, 64v+64). Lane = row within stripe;
// __ballot over lanes gives one column's 64 row-bits. Masks: T = (tgt==c),
// P = (p>=0.5); bg mask is ~T (derived later, not stored).
__global__ __launch_bounds__(256) void k_mask(const int* __restrict__ tgt,
    const float* __restrict__ pbuf, u64* __restrict__ cmT, u64* __restrict__ cmP) {
  __shared__ unsigned char seeds[HH][68];  // [row][col-in-tile], pad 68 (17 words)
  int s  = blockIdx.x;   // slice
  int wt = blockIdx.y;   // w-tile 0..3
  int n = s / 3, c = s - n * 3 + 1;
  int w0 = wt * 64;
  int v = threadIdx.x >> 6, l = threadIdx.x & 63;
  const int*   tg = tgt  + (size_t)n * HW_;
  const float* pb = pbuf + (size_t)s * HW_;
  for (int i = 0; i < 64; ++i) {
    int h = v * 64 + i;
    int off = h * WW + w0 + l;
    int   tv = tg[off];
    float pv = pb[off];
    seeds[h][l] = (unsigned char)((tv == c ? 1 : 0) | (pv >= 0.5f ? 2 : 0));
  }
  __syncthreads();
  u64 myT = 0, myP = 0;
  for (int j = 0; j < 64; ++j) {
    unsigned char b = seeds[v * 64 + l][j];
    u64 bT = __ballot((int)(b & 1));
    u64 bP = __ballot((int)(b & 2));
    if (l == j) { myT = bT; myP = bP; }
  }
  size_t ci = ((size_t)s * WW + w0 + l) * 4 + v;  // [s][w][stripe]
  cmT[ci] = myT;
  cmP[ci] = myP;
}

// Exact 1D nearest-set-bit distance in a 256-bit column mask (4xu64,
// word k covers rows 64k..64k+63, bit j = row 64k+j). Returns min(dl,dr)
// with 10000 when absent — identical semantics to the reference.
__device__ inline int dtdist(const u64 m[4], int h) {
  int word = h >> 6, bit = h & 63;
  u64 below = m[word] & ((bit == 63) ? ~0ull : ((1ull << (bit + 1)) - 1ull));
  int dl = 10000;
  for (int k = word; k >= 0; --k) {
    u64 mm = (k == word) ? below : m[k];
    if (mm) { dl = h - (k * 64 + 63 - __builtin_clzll(mm)); break; }
  }
  u64 above = m[word] & (~0ull << bit);
  int dr = 10000;
  for (int k = word; k < 4; ++k) {
    u64 mm = (k == word) ? above : m[k];
    if (mm) { dr = (k * 64 + __builtin_ctzll(mm)) - h; break; }
  }
  return min(dl, dr);
}

// Fused: column-DT from masks (registers) -> LDS row -> pruned exact row
// envelope -> bd / hd-term1 / hd-term2 reductions (spread atomics).
__global__ __launch_bounds__(256) void k_rowfused(const u64* __restrict__ cmT,
    const u64* __restrict__ cmP, const float* __restrict__ pbuf,
    const int* __restrict__ tgt, double* __restrict__ bkt) {
  __shared__ alignas(16) float lf[WW];
  __shared__ alignas(16) float lb[WW];
  __shared__ alignas(16) float lq[WW];
  __shared__ double sbuf[4];
  int bh = blockIdx.x;            // s*HH + h
  int h  = bh & (HH - 1);
  int s  = bh >> 8;
  int n = s / 3, c = s - n * 3 + 1;
  int w = threadIdx.x;
  u64 mT[4], mP[4], mB[4];
  {
    size_t ci = ((size_t)s * WW + w) * 4;
    const ulonglong2* pT = (const ulonglong2*)(cmT + ci);
    const ulonglong2* pP = (const ulonglong2*)(cmP + ci);
    ulonglong2 a0 = pT[0], a1 = pT[1];
    ulonglong2 b0 = pP[0], b1 = pP[1];
    mT[0] = a0.x; mT[1] = a0.y; mT[2] = a1.x; mT[3] = a1.y;
    mP[0] = b0.x; mP[1] = b0.y; mP[2] = b1.x; mP[3] = b1.y;
    #pragma unroll
    for (int k = 0; k < 4; ++k) mB[k] = ~mT[k];
  }
  int dF = dtdist(mT, h);
  int dB = dtdist(mB, h);
  int dP = dtdist(mP, h);
  lf[w] = (float)(dF * dF);
  lb[w] = (float)(dB * dB);
  lq[w] = (float)(dP * dP);
  __syncthreads();
  float mF = lf[w], mBv = lb[w], mQ = lq[w];
  for (int r = 1; r < WW; ++r) {
    float rr = (float)(r * r);
    if (__all(rr >= mF)) break;
    int jl = w - r, jr = w + r;
    if (jl >= 0) mF = fminf(mF, lf[jl] + rr);
    if (jr < WW) mF = fminf(mF, lf[jr] + rr);
  }
  for (int r = 1; r < WW; ++r) {
    float rr = (float)(r * r);
    if (__all(rr >= mBv)) break;
    int jl = w - r, jr = w + r;
    if (jl >= 0) mBv = fminf(mBv, lb[jl] + rr);
    if (jr < WW) mBv = fminf(mBv, lb[jr] + rr);
  }
  for (int r = 1; r < WW; ++r) {
    float rr = (float)(r * r);
    if (__all(rr >= mQ)) break;
    int jl = w - r, jr = w + r;
    if (jl >= 0) mQ = fminf(mQ, lq[jl] + rr);
    if (jr < WW) mQ = fminf(mQ, lq[jr] + rr);
  }
  size_t off = (size_t)s * HW_ + (size_t)h * WW + w;
  float dfg = sqrtf(mF), dbg = sqrtf(mBv), dpr = sqrtf(mQ);
  float p  = pbuf[off];
  float gt = (tgt[(size_t)n * HW_ + h * WW + w] == c) ? 1.0f : 0.0f;
  int b = (blockIdx.x & (NBKT - 1)) * 8;
  double r;
  r = block_reduce((double)(p * (dfg - dbg)), sbuf);   // bd
  if (threadIdx.x == 0) atomicAdd(&bkt[b + 1], r);
  r = block_reduce((double)(p * dfg * dfg), sbuf);     // hd term1
  if (threadIdx.x == 0) atomicAdd(&bkt[b + 2], r);
  r = block_reduce((double)(gt * dpr * dpr), sbuf);    // hd term2
  if (threadIdx.x == 0) atomicAdd(&bkt[b + 3], r);
}

__global__ void k_final(const double* __restrict__ bkt, float* __restrict__ out) {
  int t = threadIdx.x;  // 64 threads, one wave
  double ce = 0.0, bd = 0.0, t1 = 0.0, t2 = 0.0;
  if (t < NBKT) {
    ce = bkt[t * 8 + 0];
    bd = bkt[t * 8 + 1];
    t1 = bkt[t * 8 + 2];
    t2 = bkt[t * 8 + 3];
  }
  #pragma unroll
  for (int o = 32; o > 0; o >>= 1) {
    ce += __shfl_down(ce, o, 64);
    bd += __shfl_down(bd, o, 64);
    t1 += __shfl_down(t1, o, 64);
    t2 += __shfl_down(t2, o, 64);
  }
  if (t == 0) {
    ce /= (double)(NB * HW_);
    bd /= (double)NSL;
    double hd = (t1 + t2) / ((double)HW_ * (double)(2 * NB * (NC - 1)));
    out[0] = (float)(ce + 0.5 * bd + 0.5 * hd);
    out[1] = (float)ce;
    out[2] = (float)bd;
    out[3] = (float)hd;
  }
}

extern "C" void kernel_launch(void* const* d_in, const int* in_sizes, int n_in,
                              void* d_out, int out_size, void* d_ws, size_t ws_size,
                              hipStream_t stream) {
  (void)in_sizes; (void)n_in; (void)out_size; (void)ws_size;
  const float* pred = (const float*)d_in[0];
  const int*   tgt  = (const int*)d_in[1];
  float* out = (float*)d_out;
  char* ws = (char*)d_ws;
  double* bkt = (double*)ws;                             // 32*8 doubles = 2KB
  float* pbuf = (float*)(ws + 2048);                     // 24*HW floats = 6.3MB
  u64* cmT = (u64*)(ws + 2048 + (size_t)NSL * HW_ * 4);  // 24*256*4 u64 = 196KB
  u64* cmP = cmT + (size_t)NSL * WW * 4;                 // 196KB

  hipLaunchKernelGGL(k_zero, dim3(1), dim3(256), 0, stream, bkt);
  hipLaunchKernelGGL(k_softmax_ce, dim3((NB * HW_) / 256), dim3(256), 0, stream,
                     pred, tgt, pbuf, bkt);
  hipLaunchKernelGGL(k_mask, dim3(NSL, 4), dim3(256), 0, stream, tgt, pbuf, cmT, cmP);
  hipLaunchKernelGGL(k_rowfused, dim3(NSL * HH), dim3(256), 0, stream,
                     cmT, cmP, pbuf, tgt, bkt);
  hipLaunchKernelGGL(k_final, dim3(1), dim3(64), 0, stream, bkt, out);
}

// Round 5
// 90.581 us; speedup vs baseline: 5.8916x; 1.0608x over previous
//
#include <hip/hip_runtime.h>

#define NB 8
#define NC 4
#define HH 256
#define WW 256
#define HW_ (HH * WW)
#define NSL 24      // NB * (NC-1)
#define CT 8        // columns per k_env block
#define NT (WW/CT)  // 32 column tiles

typedef unsigned long long u64;

__device__ inline double block_reduce(double v, double* sbuf) {
  int lane = threadIdx.x & 63;
  int wid  = threadIdx.x >> 6;
  #pragma unroll
  for (int o = 32; o > 0; o >>= 1) v += __shfl_down(v, o, 64);
  if (lane == 0) sbuf[wid] = v;
  __syncthreads();
  double r = 0.0;
  if (threadIdx.x == 0) {
    #pragma unroll
    for (int i = 0; i < 4; ++i) r += sbuf[i];
  }
  __syncthreads();
  return r;  // valid in thread 0 only
}

// Block = one image row (n,h). Softmax+CE, write p[1..3], and emit bit-masks
// of this row (bit = column w) for fg (tgt==c) and pred (p_c>=0.5) via ballot.
__global__ __launch_bounds__(256) void k_softmax_ce(
    const float* __restrict__ pred, const int* __restrict__ tgt,
    float* __restrict__ pbuf, u64* __restrict__ rmT, u64* __restrict__ rmP,
    double* __restrict__ pce) {
  __shared__ double sbuf[4];
  int b = blockIdx.x;            // n*HH + h
  int n = b >> 8, h = b & (HH - 1);
  int w = threadIdx.x;
  size_t base = (size_t)n * NC * HW_ + (size_t)h * WW + w;
  float x0 = pred[base];
  float x1 = pred[base + HW_];
  float x2 = pred[base + 2 * HW_];
  float x3 = pred[base + 3 * HW_];
  float mx = fmaxf(fmaxf(x0, x1), fmaxf(x2, x3));
  float e0 = expf(x0 - mx), e1 = expf(x1 - mx), e2 = expf(x2 - mx), e3 = expf(x3 - mx);
  float sum = e0 + e1 + e2 + e3;
  float lse = mx + logf(sum);
  int t = tgt[(size_t)n * HW_ + h * WW + w];
  float xt = (t == 0) ? x0 : (t == 1) ? x1 : (t == 2) ? x2 : x3;
  float ce = lse - xt;
  float inv = 1.0f / sum;
  float p1 = e1 * inv, p2 = e2 * inv, p3 = e3 * inv;
  size_t pb = ((size_t)(n * 3)) * HW_ + (size_t)h * WW + w;
  pbuf[pb]           = p1;
  pbuf[pb + HW_]     = p2;
  pbuf[pb + 2 * HW_] = p3;
  u64 bT1 = __ballot(t == 1), bP1 = __ballot(p1 >= 0.5f);
  u64 bT2 = __ballot(t == 2), bP2 = __ballot(p2 >= 0.5f);
  u64 bT3 = __ballot(t == 3), bP3 = __ballot(p3 >= 0.5f);
  if ((threadIdx.x & 63) == 0) {
    int v = threadIdx.x >> 6;
    size_t mi = ((size_t)(n * 3) * HH + h) * 4 + v;   // slice s = n*3 + (c-1)
    rmT[mi]                     = bT1;  rmP[mi]                     = bP1;
    rmT[mi + (size_t)HH * 4]     = bT2;  rmP[mi + (size_t)HH * 4]     = bP2;
    rmT[mi + (size_t)2 * HH * 4] = bT3;  rmP[mi + (size_t)2 * HH * 4] = bP3;
  }
  double r = block_reduce((double)ce, sbuf);
  if (threadIdx.x == 0) pce[b] = r;
}

// Nearest-set-bit distance within a 256-bit row mask from position WORD*64+bit.
// Returns min(dl, dr), 10000 when empty — identical to reference semantics.
template<int WORD>
__device__ __forceinline__ int nsb(u64 m0, u64 m1, u64 m2, u64 m3, int bit) {
  int dl = 10000, dr = 10000;
  u64 cur = (WORD == 0) ? m0 : (WORD == 1) ? m1 : (WORD == 2) ? m2 : m3;
  u64 below = cur & ((bit == 63) ? ~0ull : ((1ull << (bit + 1)) - 1ull));
  if (below) { dl = bit - (63 - (int)__builtin_clzll(below)); }
  else {
    bool done = false;
    if constexpr (WORD >= 1) {
      u64 x = (WORD == 1) ? m0 : (WORD == 2) ? m1 : m2;
      if (x) { dl = bit + 1 + (int)__builtin_clzll(x); done = true; }
    }
    if constexpr (WORD >= 2) {
      if (!done) { u64 x = (WORD == 2) ? m0 : m1;
        if (x) { dl = bit + 65 + (int)__builtin_clzll(x); done = true; } }
    }
    if constexpr (WORD >= 3) {
      if (!done) { if (m0) dl = bit + 129 + (int)__builtin_clzll(m0); }
    }
    (void)done;
  }
  u64 above = cur & (~0ull << bit);
  if (above) { dr = (int)__builtin_ctzll(above) - bit; }
  else {
    bool done = false;
    if constexpr (WORD <= 2) {
      u64 x = (WORD == 0) ? m1 : (WORD == 1) ? m2 : m3;
      if (x) { dr = 64 + (int)__builtin_ctzll(x) - bit; done = true; }
    }
    if constexpr (WORD <= 1) {
      if (!done) { u64 x = (WORD == 0) ? m2 : m3;
        if (x) { dr = 128 + (int)__builtin_ctzll(x) - bit; done = true; } }
    }
    if constexpr (WORD == 0) {
      if (!done) { if (m3) dr = 192 + (int)__builtin_ctzll(m3) - bit; }
    }
    (void)done;
  }
  return min(dl, dr);
}

template<int WORD>
__device__ __forceinline__ void filltile(
    u64 t0, u64 t1, u64 t2, u64 t3, u64 p0, u64 p1, u64 p2, u64 p3,
    int h, int bit0, float gF[CT][HH], float gB[CT][HH], float gQ[CT][HH],
    unsigned char gtb[CT][HH]) {
  u64 cur = (WORD == 0) ? t0 : (WORD == 1) ? t1 : (WORD == 2) ? t2 : t3;
  #pragma unroll
  for (int wi = 0; wi < CT; ++wi) {
    int bit = bit0 + wi;
    int dF = nsb<WORD>(t0, t1, t2, t3, bit);
    int dB = nsb<WORD>(~t0, ~t1, ~t2, ~t3, bit);
    int dP = nsb<WORD>(p0, p1, p2, p3, bit);
    gF[wi][h] = (float)(dF * dF);
    gB[wi][h] = (float)(dB * dB);
    gQ[wi][h] = (float)(dP * dP);
    gtb[wi][h] = (unsigned char)((cur >> bit) & 1ull);
  }
}

// Block = (slice s, 8-column tile). Phase A: thread = row h, compute row-DT
// distances for the 8 columns from row bit-masks -> LDS. Phase B: pruned
// exact envelope along H per pixel + fused f64 accumulation; one combined
// block reduce -> per-block partials.
__global__ __launch_bounds__(256) void k_env(
    const u64* __restrict__ rmT, const u64* __restrict__ rmP,
    const float* __restrict__ pbuf, double* __restrict__ part) {
  __shared__ float gF[CT][HH];
  __shared__ float gB[CT][HH];
  __shared__ float gQ[CT][HH];
  __shared__ float pp[CT][HH];
  __shared__ unsigned char gtb[CT][HH];
  __shared__ double sbuf[12];
  int s  = blockIdx.x;
  int w0 = blockIdx.y * CT;
  int h  = threadIdx.x;
  // --- phase A ---
  {
    size_t mi = ((size_t)s * HH + h) * 4;
    const ulonglong2* pT = (const ulonglong2*)(rmT + mi);
    const ulonglong2* pP = (const ulonglong2*)(rmP + mi);
    ulonglong2 a0 = pT[0], a1 = pT[1];
    ulonglong2 b0 = pP[0], b1 = pP[1];
    const float* prow = pbuf + (size_t)s * HW_ + (size_t)h * WW + w0;
    float4 pa = *(const float4*)prow;
    float4 pc = *(const float4*)(prow + 4);
    pp[0][h] = pa.x; pp[1][h] = pa.y; pp[2][h] = pa.z; pp[3][h] = pa.w;
    pp[4][h] = pc.x; pp[5][h] = pc.y; pp[6][h] = pc.z; pp[7][h] = pc.w;
    int bit0 = w0 & 63;
    switch (w0 >> 6) {
      case 0: filltile<0>(a0.x,a0.y,a1.x,a1.y,b0.x,b0.y,b1.x,b1.y,h,bit0,gF,gB,gQ,gtb); break;
      case 1: filltile<1>(a0.x,a0.y,a1.x,a1.y,b0.x,b0.y,b1.x,b1.y,h,bit0,gF,gB,gQ,gtb); break;
      case 2: filltile<2>(a0.x,a0.y,a1.x,a1.y,b0.x,b0.y,b1.x,b1.y,h,bit0,gF,gB,gQ,gtb); break;
      default: filltile<3>(a0.x,a0.y,a1.x,a1.y,b0.x,b0.y,b1.x,b1.y,h,bit0,gF,gB,gQ,gtb); break;
    }
  }
  __syncthreads();
  // --- phase B ---
  int wi = threadIdx.x & (CT - 1);
  int hg = threadIdx.x / CT;           // 0..31, each owns 8 rows
  double a_bd = 0.0, a_t1 = 0.0, a_t2 = 0.0;
  for (int k = 0; k < 8; ++k) {
    int h2 = hg * 8 + k;
    float mF = gF[wi][h2], mB = gB[wi][h2], mQ = gQ[wi][h2];
    for (int r = 1; r < HH; ++r) {
      float rr = (float)(r * r);
      if (rr >= mF) break;
      int u = h2 - r, d = h2 + r;
      if (u >= 0) mF = fminf(mF, gF[wi][u] + rr);
      if (d < HH) mF = fminf(mF, gF[wi][d] + rr);
    }
    for (int r = 1; r < HH; ++r) {
      float rr = (float)(r * r);
      if (rr >= mB) break;
      int u = h2 - r, d = h2 + r;
      if (u >= 0) mB = fminf(mB, gB[wi][u] + rr);
      if (d < HH) mB = fminf(mB, gB[wi][d] + rr);
    }
    for (int r = 1; r < HH; ++r) {
      float rr = (float)(r * r);
      if (rr >= mQ) break;
      int u = h2 - r, d = h2 + r;
      if (u >= 0) mQ = fminf(mQ, gQ[wi][u] + rr);
      if (d < HH) mQ = fminf(mQ, gQ[wi][d] + rr);
    }
    float dfg = sqrtf(mF), dbg = sqrtf(mB), dpr = sqrtf(mQ);
    float p  = pp[wi][h2];
    float gt = (float)gtb[wi][h2];
    a_bd += (double)(p * (dfg - dbg));
    a_t1 += (double)(p * dfg * dfg);
    a_t2 += (double)(gt * dpr * dpr);
  }
  int lane = threadIdx.x & 63, wid = threadIdx.x >> 6;
  #pragma unroll
  for (int o = 32; o > 0; o >>= 1) {
    a_bd += __shfl_down(a_bd, o, 64);
    a_t1 += __shfl_down(a_t1, o, 64);
    a_t2 += __shfl_down(a_t2, o, 64);
  }
  if (lane == 0) { sbuf[wid*3] = a_bd; sbuf[wid*3+1] = a_t1; sbuf[wid*3+2] = a_t2; }
  __syncthreads();
  if (threadIdx.x == 0) {
    double b = 0, t1 = 0, t2 = 0;
    #pragma unroll
    for (int i = 0; i < 4; ++i) { b += sbuf[i*3]; t1 += sbuf[i*3+1]; t2 += sbuf[i*3+2]; }
    size_t pi = ((size_t)s * NT + blockIdx.y) * 4;
    part[pi] = b; part[pi+1] = t1; part[pi+2] = t2;
  }
}

__global__ __launch_bounds__(256) void k_final(const double* __restrict__ pce,
    const double* __restrict__ part, float* __restrict__ out) {
  __shared__ double sb[16];
  int t = threadIdx.x;
  double ce = 0.0, bd = 0.0, t1 = 0.0, t2 = 0.0;
  for (int i = t; i < NB * HH; i += 256) ce += pce[i];
  for (int i = t; i < NSL * NT; i += 256) {
    bd += part[(size_t)i * 4];
    t1 += part[(size_t)i * 4 + 1];
    t2 += part[(size_t)i * 4 + 2];
  }
  int lane = t & 63, wid = t >> 6;
  #pragma unroll
  for (int o = 32; o > 0; o >>= 1) {
    ce += __shfl_down(ce, o, 64);
    bd += __shfl_down(bd, o, 64);
    t1 += __shfl_down(t1, o, 64);
    t2 += __shfl_down(t2, o, 64);
  }
  if (lane == 0) { sb[wid*4]=ce; sb[wid*4+1]=bd; sb[wid*4+2]=t1; sb[wid*4+3]=t2; }
  __syncthreads();
  if (t == 0) {
    double c = 0, b = 0, u1 = 0, u2 = 0;
    #pragma unroll
    for (int i = 0; i < 4; ++i) { c += sb[i*4]; b += sb[i*4+1]; u1 += sb[i*4+2]; u2 += sb[i*4+3]; }
    c /= (double)(NB * HW_);
    b /= (double)NSL;
    double hd = (u1 + u2) / ((double)HW_ * (double)(2 * NB * (NC - 1)));
    out[0] = (float)(c + 0.5 * b + 0.5 * hd);
    out[1] = (float)c;
    out[2] = (float)b;
    out[3] = (float)hd;
  }
}

extern "C" void kernel_launch(void* const* d_in, const int* in_sizes, int n_in,
                              void* d_out, int out_size, void* d_ws, size_t ws_size,
                              hipStream_t stream) {
  (void)in_sizes; (void)n_in; (void)out_size; (void)ws_size;
  const float* pred = (const float*)d_in[0];
  const int*   tgt  = (const int*)d_in[1];
  float* out = (float*)d_out;
  char* ws = (char*)d_ws;
  double* pce  = (double*)ws;                            // 2048 doubles (16KB)
  double* part = (double*)(ws + 16384);                  // 768*4 doubles (24KB)
  float*  pbuf = (float*)(ws + 65536);                   // 24*HW floats (6.29MB)
  u64* rmT = (u64*)(ws + 65536 + (size_t)NSL * HW_ * 4); // 24*256*4 u64 (196KB)
  u64* rmP = rmT + (size_t)NSL * HH * 4;                 // 196KB

  hipLaunchKernelGGL(k_softmax_ce, dim3(NB * HH), dim3(256), 0, stream,
                     pred, tgt, pbuf, rmT, rmP, pce);
  hipLaunchKernelGGL(k_env, dim3(NSL, NT), dim3(256), 0, stream,
                     rmT, rmP, pbuf, part);
  hipLaunchKernelGGL(k_final, dim3(1), dim3(256), 0, stream, pce, part, out);
}